// Round 6
// baseline (5987.494 us; speedup 1.0000x reference)
//
#include <hip/hip_runtime.h>
#include <hip/hip_bf16.h>
#include <stdint.h>

// Problem constants
#define BATCH 256
#define SEQT  200
#define IND   128
#define HID   256
#define G3    768   // 3*HID
#define OUTD  118

#define HSTRIDE 264  // h-state LDS row stride in shorts (16B-aligned; 132 dw ≡ 4 mod 32)
#define W0SZ (G3*IND)
#define WHSZ (G3*HID)

#define LOG2E  1.44269504f
#define NLOG2E (-1.44269504f)
#define LOG2E2 2.88539008f

typedef short  short8 __attribute__((ext_vector_type(8)));
typedef float  f32x4  __attribute__((ext_vector_type(4)));
typedef int    i32x4  __attribute__((ext_vector_type(4)));

__device__ __forceinline__ float exp2fast(float x) {
#if __has_builtin(__builtin_amdgcn_exp2f)
    return __builtin_amdgcn_exp2f(x);
#else
    return exp2f(x);
#endif
}

__device__ __forceinline__ unsigned short f2bf(float x) {
    union { float f; uint32_t u; } v; v.f = x;
    uint32_t u = v.u;
    u += 0x7FFF + ((u >> 16) & 1);   // round-to-nearest-even
    return (unsigned short)(u >> 16);
}

// One fused conversion kernel for all four weight matrices.
__global__ void cvt_weights(const float* __restrict__ w0,  const float* __restrict__ wh0,
                            const float* __restrict__ w1,  const float* __restrict__ wh1,
                            unsigned short* __restrict__ o0,  unsigned short* __restrict__ oh0,
                            unsigned short* __restrict__ o1,  unsigned short* __restrict__ oh1) {
    int i = blockIdx.x * blockDim.x + threadIdx.x;
    const int n = W0SZ + 3 * WHSZ;
    int stride = gridDim.x * blockDim.x;
    for (; i < n; i += stride) {
        int j = i;
        if (j < W0SZ) { o0[j] = f2bf(w0[j]); continue; }
        j -= W0SZ;
        if (j < WHSZ) { oh0[j] = f2bf(wh0[j]); continue; }
        j -= WHSZ;
        if (j < WHSZ) { o1[j] = f2bf(w1[j]); continue; }
        j -= WHSZ;
        oh1[j] = f2bf(wh1[j]);
    }
}

// bc = bih + bhh for r,z gates (j < 512); bc = bih for n gate. Both layers.
__global__ void combine_bias(const float* __restrict__ bih0, const float* __restrict__ bhh0,
                             const float* __restrict__ bih1, const float* __restrict__ bhh1,
                             float* __restrict__ bc0, float* __restrict__ bc1) {
    int i = blockIdx.x * blockDim.x + threadIdx.x;
    if (i < G3) bc0[i] = bih0[i] + (i < 2 * HID ? bhh0[i] : 0.0f);
    else if (i < 2 * G3) {
        int j = i - G3;
        bc1[j] = bih1[j] + (j < 2 * HID ? bhh1[j] : 0.0f);
    }
}

// C[M,768]: r,z cols = A@Bt^T + bias (raw, bias folded — scan seeds MFMA C with it);
//           n  cols = 2*log2e * (A@Bt^T + bias) (pre-scaled exp2 arg).
template<int K, bool AF32>
__global__ __launch_bounds__(256) void gemm_bf16(
    const void* __restrict__ Av,
    const unsigned short* __restrict__ Bt,
    const float* __restrict__ bias,
    float* __restrict__ C)
{
    const int mt   = blockIdx.x;
    const int wave = threadIdx.x >> 6;
    const int lane = threadIdx.x & 63;
    const int col  = lane & 15;
    const int quad = lane >> 4;
    const int m0   = mt * 64 + wave * 16;
    constexpr int KS = K / 32;

    short8 a[KS];
    if constexpr (AF32) {
        const float* arow = (const float*)Av + (size_t)(m0 + col) * K;
#pragma unroll
        for (int ks = 0; ks < KS; ks++) {
            f32x4 lo = *(const f32x4*)(arow + ks * 32 + quad * 8);
            f32x4 hi = *(const f32x4*)(arow + ks * 32 + quad * 8 + 4);
#pragma unroll
            for (int e = 0; e < 4; e++) {
                a[ks][e]     = (short)f2bf(lo[e]);
                a[ks][e + 4] = (short)f2bf(hi[e]);
            }
        }
    } else {
        const unsigned short* arow = (const unsigned short*)Av + (size_t)(m0 + col) * K;
#pragma unroll
        for (int ks = 0; ks < KS; ks++)
            a[ks] = *(const short8*)(arow + ks * 32 + quad * 8);
    }

#pragma unroll
    for (int nb = 0; nb < 6; nb++) {
        f32x4 acc[8];
#pragma unroll
        for (int nt = 0; nt < 8; nt++) acc[nt] = (f32x4)(0.0f);
#pragma unroll
        for (int ks = 0; ks < KS; ks++) {
#pragma unroll
            for (int nt = 0; nt < 8; nt++) {
                const unsigned short* bp =
                    Bt + (size_t)(nb * 128 + nt * 16 + col) * K + ks * 32 + quad * 8;
                short8 b = *(const short8*)bp;
                acc[nt] = __builtin_amdgcn_mfma_f32_16x16x32_bf16(a[ks], b, acc[nt], 0, 0, 0);
            }
        }
#pragma unroll
        for (int nt = 0; nt < 8; nt++) {
            int g = nb * 128 + nt * 16 + col;
            float bia = bias[g];
#pragma unroll
            for (int r = 0; r < 4; r++) {
                int m = m0 + quad * 4 + r;
                float v = acc[nt][r] + bia;
                C[(size_t)m * G3 + g] = (nb < 4) ? v : v * LOG2E2;
            }
        }
    }
}

// GRU scan. 16 WGs x 512 threads (8 waves, 2/SIMD).
// WG owns batches [wg*16,+16); wave owns 32 j-cols (jt0/jt1) x 3 gates.
// ALL Whh weights AGPR-pinned (48 i32x4 = 192 AGPRs; MFMA reads B from AGPR).
// LDS: only the double-buffered bf16 h (2 x 8.25KB).
// gx: cross-step double-buffered; r,z values seed the MFMA C operand.
__global__ __launch_bounds__(512, 2) void gru_scan(
    const float* __restrict__ gx,            // [B*T,768]: r,z raw (+bias), n pre-scaled
    const unsigned short* __restrict__ Whh,  // [768,256] bf16
    const float* __restrict__ bhh,           // [768] (only n-part used)
    unsigned short* __restrict__ h1_out,     // [B*T,256] bf16 or nullptr
    float* __restrict__ hlast)               // [B,256] fp32 or nullptr
{
    __shared__ unsigned short hs[2][16 * HSTRIDE];   // 16,896 B

    const int b0    = blockIdx.x * 16;
    const int tid   = threadIdx.x;
    const int wave  = tid >> 6;
    const int lane  = tid & 63;
    const int col   = lane & 15;
    const int quad  = lane >> 4;
    const int jbase = wave * 32;
    const int j0    = jbase + col;

    // all Whh slices -> AGPR-resident (3 gates x 2 jt x 8 ks = 192 regs)
    i32x4 w[3][2][8];
#pragma unroll
    for (int g = 0; g < 3; g++)
#pragma unroll
        for (int jt = 0; jt < 2; jt++)
#pragma unroll
            for (int ks = 0; ks < 8; ks++)
                w[g][jt][ks] = *(const i32x4*)(
                    Whh + (size_t)(g * HID + jbase + jt * 16 + col) * HID + ks * 32 + quad * 8);

    for (int i = tid; i < 16 * HSTRIDE; i += 512) hs[0][i] = 0;

    float hreg[2][4] = {};
    const float bhn0 = bhh[2 * HID + j0];
    const float bhn1 = bhh[2 * HID + j0 + 16];

    const float* gp[4];
    int hof[4];
#pragma unroll
    for (int r = 0; r < 4; r++) {
        int row = (b0 + quad * 4 + r) * SEQT;
        gp[r]  = gx + (size_t)row * G3 + j0;
        hof[r] = row * HID + j0;
    }
    const int abase = col * HSTRIDE + quad * 8;      // A-frag read base (shorts)
    const int wbase = (quad * 4) * HSTRIDE + j0;     // h write base

    // prologue: gx for t=0
    float gA[3][2][4], gB[3][2][4];   // [gate][jt][r]
#pragma unroll
    for (int r = 0; r < 4; r++)
#pragma unroll
        for (int g3 = 0; g3 < 3; g3++) {
            gA[g3][0][r] = gp[r][g3 * HID];
            gA[g3][1][r] = gp[r][g3 * HID + 16];
        }
#pragma unroll
    for (int r = 0; r < 4; r++) gp[r] += G3;

    __syncthreads();

    auto step = [&](int t, float (&gc)[3][2][4], float (&gn)[3][2][4],
                    const unsigned short* hc, unsigned short* hn) {
        // AGPR pins: opaque per-iter redefinition, no data movement
#pragma unroll
        for (int g = 0; g < 3; g++)
#pragma unroll
            for (int jt = 0; jt < 2; jt++)
#pragma unroll
                for (int ks = 0; ks < 8; ks++)
                    asm volatile("" : "+a"(w[g][jt][ks]));

        // prefetch gx for t+1 (consumed a full step later; tail step reads
        // harmlessly into the adjacent ws buffer)
#pragma unroll
        for (int r = 0; r < 4; r++)
#pragma unroll
            for (int g3 = 0; g3 < 3; g3++) {
                gn[g3][0][r] = gp[r][g3 * HID];
                gn[g3][1][r] = gp[r][g3 * HID + 16];
            }
#pragma unroll
        for (int r = 0; r < 4; r++) gp[r] += G3;

        // seed accumulators: r,z with gx pre-activations, n with bhh_n splat
        f32x4 acc[3][2];
#pragma unroll
        for (int jt = 0; jt < 2; jt++) {
            acc[0][jt] = (f32x4){ gc[0][jt][0], gc[0][jt][1], gc[0][jt][2], gc[0][jt][3] };
            acc[1][jt] = (f32x4){ gc[1][jt][0], gc[1][jt][1], gc[1][jt][2], gc[1][jt][3] };
        }
        acc[2][0] = (f32x4)(bhn0);
        acc[2][1] = (f32x4)(bhn1);

#pragma unroll
        for (int ks = 0; ks < 8; ks++) {
            short8 a = *(const short8*)(&hc[abase + ks * 32]);
            acc[0][0] = __builtin_amdgcn_mfma_f32_16x16x32_bf16(a, __builtin_bit_cast(short8, w[0][0][ks]), acc[0][0], 0, 0, 0);
            acc[0][1] = __builtin_amdgcn_mfma_f32_16x16x32_bf16(a, __builtin_bit_cast(short8, w[0][1][ks]), acc[0][1], 0, 0, 0);
            acc[1][0] = __builtin_amdgcn_mfma_f32_16x16x32_bf16(a, __builtin_bit_cast(short8, w[1][0][ks]), acc[1][0], 0, 0, 0);
            acc[1][1] = __builtin_amdgcn_mfma_f32_16x16x32_bf16(a, __builtin_bit_cast(short8, w[1][1][ks]), acc[1][1], 0, 0, 0);
            acc[2][0] = __builtin_amdgcn_mfma_f32_16x16x32_bf16(a, __builtin_bit_cast(short8, w[2][0][ks]), acc[2][0], 0, 0, 0);
            acc[2][1] = __builtin_amdgcn_mfma_f32_16x16x32_bf16(a, __builtin_bit_cast(short8, w[2][1][ks]), acc[2][1], 0, 0, 0);
        }

        unsigned short hb[2][4];
#pragma unroll
        for (int jt = 0; jt < 2; jt++)
#pragma unroll
            for (int r = 0; r < 4; r++) {
                // acc0/acc1 = full r,z pre-activation; sigmoid via exp2
                float er = exp2fast(acc[0][jt][r] * NLOG2E);
                float rr = __builtin_amdgcn_rcpf(1.0f + er);
                float ez = exp2fast(acc[1][jt][r] * NLOG2E);
                float zz = __builtin_amdgcn_rcpf(1.0f + ez);
                // acc2 = gh_n + bhh_n; gc[2] = 2*log2e*(gx_n + bih_n)
                float en = exp2fast(__builtin_fmaf(rr * acc[2][jt][r], LOG2E2, gc[2][jt][r]));
                float nn = __builtin_fmaf(__builtin_amdgcn_rcpf(1.0f + en), -2.0f, 1.0f);
                float hnew = __builtin_fmaf(zz, hreg[jt][r] - nn, nn);
                hreg[jt][r] = hnew;
                hb[jt][r] = f2bf(hnew);
                hn[wbase + r * HSTRIDE + jt * 16] = hb[jt][r];
            }

        if (h1_out) {
#pragma unroll
            for (int jt = 0; jt < 2; jt++)
#pragma unroll
                for (int r = 0; r < 4; r++)
                    h1_out[hof[r] + jt * 16] = hb[jt][r];
        }
#pragma unroll
        for (int r = 0; r < 4; r++) hof[r] += HID;

        if (hlast && t == SEQT - 1) {
#pragma unroll
            for (int jt = 0; jt < 2; jt++)
#pragma unroll
                for (int r = 0; r < 4; r++)
                    hlast[(b0 + quad * 4 + r) * HID + j0 + jt * 16] = hreg[jt][r];
        }

        __syncthreads();
    };

    for (int t = 0; t < SEQT; t += 2) {
        step(t,     gA, gB, hs[0], hs[1]);
        step(t + 1, gB, gA, hs[1], hs[0]);
    }
}

// out[256,118] = hlast[256,256] @ fcW[118,256]^T + fcb
__global__ __launch_bounds__(128) void fc_kernel(
    const float* __restrict__ hlast, const float* __restrict__ W,
    const float* __restrict__ b, float* __restrict__ out)
{
    __shared__ float hsm[HID];
    int bidx = blockIdx.x;
    for (int i = threadIdx.x; i < HID; i += 128) hsm[i] = hlast[(size_t)bidx * HID + i];
    __syncthreads();
    int o = threadIdx.x;
    if (o < OUTD) {
        float acc = b[o];
        const float* wrow = W + (size_t)o * HID;
#pragma unroll 4
        for (int k = 0; k < HID; k++) acc += hsm[k] * wrow[k];
        out[(size_t)bidx * OUTD + o] = acc;
    }
}

extern "C" void kernel_launch(void* const* d_in, const int* in_sizes, int n_in,
                              void* d_out, int out_size, void* d_ws, size_t ws_size,
                              hipStream_t stream) {
    const float* x    = (const float*)d_in[0];
    const float* Wih0 = (const float*)d_in[1];
    const float* Whh0 = (const float*)d_in[2];
    const float* bih0 = (const float*)d_in[3];
    const float* bhh0 = (const float*)d_in[4];
    const float* Wih1 = (const float*)d_in[5];
    const float* Whh1 = (const float*)d_in[6];
    const float* bih1 = (const float*)d_in[7];
    const float* bhh1 = (const float*)d_in[8];
    const float* fcW  = (const float*)d_in[9];
    const float* fcb  = (const float*)d_in[10];
    float* out = (float*)d_out;

    char* ws = (char*)d_ws;
    size_t off = 0;
    auto walloc = [&](size_t bytes) {
        void* p = ws + off;
        off = (off + bytes + 255) & ~(size_t)255;
        return p;
    };

    const int M = BATCH * SEQT;                       // 51200
    float*          gxb  = (float*)         walloc((size_t)M * G3 * 4);   // 157.3 MB
    unsigned short* h1b  = (unsigned short*)walloc((size_t)M * HID * 2);  //  26.2 MB
    unsigned short* w0b  = (unsigned short*)walloc((size_t)W0SZ * 2);
    unsigned short* wh0b = (unsigned short*)walloc((size_t)WHSZ * 2);
    unsigned short* w1b  = (unsigned short*)walloc((size_t)WHSZ * 2);
    unsigned short* wh1b = (unsigned short*)walloc((size_t)WHSZ * 2);
    float*          bc0  = (float*)         walloc(G3 * 4);
    float*          bc1  = (float*)         walloc(G3 * 4);
    float*          hlast= (float*)         walloc((size_t)BATCH * HID * 4);

    cvt_weights <<<2688, 256, 0, stream>>>(Wih0, Whh0, Wih1, Whh1, w0b, wh0b, w1b, wh1b);
    combine_bias<<<6,    256, 0, stream>>>(bih0, bhh0, bih1, bhh1, bc0, bc1);

    // layer 0 (A = x, fp32 read + in-register cvt)
    gemm_bf16<IND, true ><<<M / 64, 256, 0, stream>>>(x, w0b, bc0, gxb);
    gru_scan<<<16, 512, 0, stream>>>(gxb, wh0b, bhh0, h1b, nullptr);

    // layer 1
    gemm_bf16<HID, false><<<M / 64, 256, 0, stream>>>(h1b, w1b, bc1, gxb);
    gru_scan<<<16, 512, 0, stream>>>(gxb, wh1b, bhh1, nullptr, hlast);

    fc_kernel<<<BATCH, 128, 0, stream>>>(hlast, fcW, fcb, out);
}

// Round 8
// 1291.522 us; speedup vs baseline: 4.6360x; 4.6360x over previous
//
#include <hip/hip_runtime.h>
#include <hip/hip_bf16.h>
#include <stdint.h>

// Problem constants
#define BATCH 256
#define SEQT  200
#define IND   128
#define HID   256
#define G3    768   // 3*HID
#define OUTD  118

#define HSTRIDE 264  // h-state LDS row stride in shorts (16B-aligned)
#define W0SZ (G3*IND)
#define WHSZ (G3*HID)

#define LOG2E  1.44269504f
#define NLOG2E (-1.44269504f)
#define LOG2E2 2.88539008f

typedef short  s16x4  __attribute__((ext_vector_type(4)));
typedef short  short8 __attribute__((ext_vector_type(8)));
typedef float  f32x4  __attribute__((ext_vector_type(4)));
typedef int    i32x4  __attribute__((ext_vector_type(4)));

__device__ __forceinline__ float exp2fast(float x) {
#if __has_builtin(__builtin_amdgcn_exp2f)
    return __builtin_amdgcn_exp2f(x);
#else
    return exp2f(x);
#endif
}

__device__ __forceinline__ unsigned short f2bf(float x) {
    union { float f; uint32_t u; } v; v.f = x;
    uint32_t u = v.u;
    u += 0x7FFF + ((u >> 16) & 1);   // round-to-nearest-even
    return (unsigned short)(u >> 16);
}

// One fused conversion kernel for all four weight matrices.
__global__ void cvt_weights(const float* __restrict__ w0,  const float* __restrict__ wh0,
                            const float* __restrict__ w1,  const float* __restrict__ wh1,
                            unsigned short* __restrict__ o0,  unsigned short* __restrict__ oh0,
                            unsigned short* __restrict__ o1,  unsigned short* __restrict__ oh1) {
    int i = blockIdx.x * blockDim.x + threadIdx.x;
    const int n = W0SZ + 3 * WHSZ;
    int stride = gridDim.x * blockDim.x;
    for (; i < n; i += stride) {
        int j = i;
        if (j < W0SZ) { o0[j] = f2bf(w0[j]); continue; }
        j -= W0SZ;
        if (j < WHSZ) { oh0[j] = f2bf(wh0[j]); continue; }
        j -= WHSZ;
        if (j < WHSZ) { o1[j] = f2bf(w1[j]); continue; }
        j -= WHSZ;
        oh1[j] = f2bf(wh1[j]);
    }
}

// bc = bih + bhh for r,z gates (j < 512); bc = bih for n gate. Both layers.
__global__ void combine_bias(const float* __restrict__ bih0, const float* __restrict__ bhh0,
                             const float* __restrict__ bih1, const float* __restrict__ bhh1,
                             float* __restrict__ bc0, float* __restrict__ bc1) {
    int i = blockIdx.x * blockDim.x + threadIdx.x;
    if (i < G3) bc0[i] = bih0[i] + (i < 2 * HID ? bhh0[i] : 0.0f);
    else if (i < 2 * G3) {
        int j = i - G3;
        bc1[j] = bih1[j] + (j < 2 * HID ? bhh1[j] : 0.0f);
    }
}

// C[M,768] = scale[g] * (A[M,K] @ Bt[768,K]^T + bias[g])
// scale = -log2e (r,z) / +2*log2e (n): pre-scaled exp2 args for gru_scan.
template<int K, bool AF32>
__global__ __launch_bounds__(256) void gemm_bf16(
    const void* __restrict__ Av,
    const unsigned short* __restrict__ Bt,
    const float* __restrict__ bias,
    float* __restrict__ C)
{
    const int mt   = blockIdx.x;
    const int wave = threadIdx.x >> 6;
    const int lane = threadIdx.x & 63;
    const int col  = lane & 15;
    const int quad = lane >> 4;
    const int m0   = mt * 64 + wave * 16;
    constexpr int KS = K / 32;

    short8 a[KS];
    if constexpr (AF32) {
        const float* arow = (const float*)Av + (size_t)(m0 + col) * K;
#pragma unroll
        for (int ks = 0; ks < KS; ks++) {
            f32x4 lo = *(const f32x4*)(arow + ks * 32 + quad * 8);
            f32x4 hi = *(const f32x4*)(arow + ks * 32 + quad * 8 + 4);
#pragma unroll
            for (int e = 0; e < 4; e++) {
                a[ks][e]     = (short)f2bf(lo[e]);
                a[ks][e + 4] = (short)f2bf(hi[e]);
            }
        }
    } else {
        const unsigned short* arow = (const unsigned short*)Av + (size_t)(m0 + col) * K;
#pragma unroll
        for (int ks = 0; ks < KS; ks++)
            a[ks] = *(const short8*)(arow + ks * 32 + quad * 8);
    }

#pragma unroll
    for (int nb = 0; nb < 6; nb++) {
        const float scl = (nb < 4) ? NLOG2E : LOG2E2;
        f32x4 acc[8];
#pragma unroll
        for (int nt = 0; nt < 8; nt++) acc[nt] = (f32x4)(0.0f);
#pragma unroll
        for (int ks = 0; ks < KS; ks++) {
#pragma unroll
            for (int nt = 0; nt < 8; nt++) {
                const unsigned short* bp =
                    Bt + (size_t)(nb * 128 + nt * 16 + col) * K + ks * 32 + quad * 8;
                short8 b = *(const short8*)bp;
                acc[nt] = __builtin_amdgcn_mfma_f32_16x16x32_bf16(a[ks], b, acc[nt], 0, 0, 0);
            }
        }
#pragma unroll
        for (int nt = 0; nt < 8; nt++) {
            int g = nb * 128 + nt * 16 + col;
            float bia = bias[g];
#pragma unroll
            for (int r = 0; r < 4; r++) {
                int m = m0 + quad * 4 + r;
                C[(size_t)m * G3 + g] = (acc[nt][r] + bia) * scl;
            }
        }
    }
}

// GRU scan, transposed-D version. 16 WGs x 512 threads (8 waves, 2/SIMD).
// WG owns batches [wg*16,+16); wave owns 32 j-cols (jt0/jt1) x 3 gates.
// MFMA: A = Whh fragment (m=j), B = h fragment (n=batch) => D[m=j][n=batch]:
// lane owns batch = lane&15, j = jbase + jt*16 + quad*4 + r (4 CONSECUTIVE j).
// => LDS h-writes are ds_write_b64, gx loads are f32x4, h1/hlast vectorized.
// Weights: r,z (both jt) + n jt0 = 160 regs AGPR-pinned ONCE before the loop
// (opaque asm result cannot be rematerialized; no per-step pin/copy churn).
// n jt1 in LDS (64KB). h double-buffered in LDS; 1 barrier/step.
__global__ __launch_bounds__(512, 2) void gru_scan(
    const float* __restrict__ gx,            // [B*T,768]: r,z scaled -log2e; n scaled 2log2e
    const unsigned short* __restrict__ Whh,  // [768,256] bf16
    const float* __restrict__ bhh,           // [768] (only n-part used)
    unsigned short* __restrict__ h1_out,     // [B*T,256] bf16 or nullptr
    float* __restrict__ hlast)               // [B,256] fp32 or nullptr
{
    __shared__ unsigned short hs[2][16 * HSTRIDE];   // 16,896 B
    __shared__ unsigned short wn1[8 * 8 * 512];      // 65,536 B (n-gate jt1)

    const int b0    = blockIdx.x * 16;
    const int tid   = threadIdx.x;
    const int wave  = tid >> 6;
    const int lane  = tid & 63;
    const int col   = lane & 15;   // = batch-in-tile (D col) and A-frag m (j row)
    const int quad  = lane >> 4;
    const int jbase = wave * 32;

    // r,z weights (both jt) + n jt0 -> AGPR-pinned: 160 regs
    i32x4 wrz[2][2][8];   // [gate][jt][ks]
#pragma unroll
    for (int g = 0; g < 2; g++)
#pragma unroll
        for (int jt = 0; jt < 2; jt++)
#pragma unroll
            for (int ks = 0; ks < 8; ks++)
                wrz[g][jt][ks] = *(const i32x4*)(
                    Whh + (size_t)(g * HID + jbase + jt * 16 + col) * HID + ks * 32 + quad * 8);
    i32x4 wn0[8];
#pragma unroll
    for (int ks = 0; ks < 8; ks++)
        wn0[ks] = *(const i32x4*)(
            Whh + (size_t)(2 * HID + jbase + col) * HID + ks * 32 + quad * 8);

    // pin ONCE: values become opaque asm results -> must stay resident
#pragma unroll
    for (int g = 0; g < 2; g++)
#pragma unroll
        for (int jt = 0; jt < 2; jt++)
#pragma unroll
            for (int ks = 0; ks < 8; ks++)
                asm volatile("" : "+a"(wrz[g][jt][ks]));
#pragma unroll
    for (int ks = 0; ks < 8; ks++)
        asm volatile("" : "+a"(wn0[ks]));

    // n-gate jt1 -> LDS, per-lane-contiguous fragment order (conflict-free)
    const int wnbase = wave * 4096 + lane * 8;   // shorts
#pragma unroll
    for (int ks = 0; ks < 8; ks++)
        *(short8*)&wn1[wnbase + ks * 512] =
            *(const short8*)(Whh + (size_t)(2 * HID + jbase + 16 + col) * HID + ks * 32 + quad * 8);

    for (int i = tid; i < 16 * HSTRIDE; i += 512) hs[0][i] = 0;

    float hreg[2][4] = {};          // [jt][r]: h for batch=b0+col, j=jbase+jt*16+quad*4+r
    f32x4 bhnv[2];                  // n-gate bhh, 4 consecutive j
#pragma unroll
    for (int jt = 0; jt < 2; jt++)
        bhnv[jt] = *(const f32x4*)(bhh + 2 * HID + jbase + jt * 16 + quad * 4);

    // lane-private pointers (batch = b0+col)
    const float* gpp = gx + (size_t)(b0 + col) * SEQT * G3 + jbase + quad * 4;
    int hof = (b0 + col) * SEQT * HID + jbase + quad * 4;

    const int bbase = col * HSTRIDE + quad * 8;              // h B-frag read base (shorts)
    const int wrow  = col * HSTRIDE + jbase + quad * 4;      // h write base (shorts)

    __syncthreads();

    for (int t = 0; t < SEQT; t++) {
        const unsigned short* hc = hs[t & 1];
        unsigned short*       hn = hs[(t & 1) ^ 1];

        // gx loads at step top; consumed in the gate phase ~1.5k cycles later
        f32x4 gc0[2], gc1[2], gc2[2];
#pragma unroll
        for (int jt = 0; jt < 2; jt++) {
            gc0[jt] = *(const f32x4*)(gpp + jt * 16);
            gc1[jt] = *(const f32x4*)(gpp + HID + jt * 16);
            gc2[jt] = *(const f32x4*)(gpp + 2 * HID + jt * 16);
        }
        gpp += G3;

        f32x4 acc[3][2];
#pragma unroll
        for (int jt = 0; jt < 2; jt++) {
            acc[0][jt] = (f32x4)(0.0f);
            acc[1][jt] = (f32x4)(0.0f);
            acc[2][jt] = bhnv[jt];    // seed n with bhh_n (free add)
        }

#pragma unroll
        for (int ks = 0; ks < 8; ks++) {
            short8 hfrag = *(const short8*)(&hc[bbase + ks * 32]);
            acc[0][0] = __builtin_amdgcn_mfma_f32_16x16x32_bf16(__builtin_bit_cast(short8, wrz[0][0][ks]), hfrag, acc[0][0], 0, 0, 0);
            acc[0][1] = __builtin_amdgcn_mfma_f32_16x16x32_bf16(__builtin_bit_cast(short8, wrz[0][1][ks]), hfrag, acc[0][1], 0, 0, 0);
            acc[1][0] = __builtin_amdgcn_mfma_f32_16x16x32_bf16(__builtin_bit_cast(short8, wrz[1][0][ks]), hfrag, acc[1][0], 0, 0, 0);
            acc[1][1] = __builtin_amdgcn_mfma_f32_16x16x32_bf16(__builtin_bit_cast(short8, wrz[1][1][ks]), hfrag, acc[1][1], 0, 0, 0);
            acc[2][0] = __builtin_amdgcn_mfma_f32_16x16x32_bf16(__builtin_bit_cast(short8, wn0[ks]),       hfrag, acc[2][0], 0, 0, 0);
            short8 b1 = *(const short8*)&wn1[wnbase + ks * 512];
            acc[2][1] = __builtin_amdgcn_mfma_f32_16x16x32_bf16(b1, hfrag, acc[2][1], 0, 0, 0);
        }

        // gate math; lane's 8 outputs are (batch=b0+col, j=jbase+jt*16+quad*4+r)
#pragma unroll
        for (int jt = 0; jt < 2; jt++) {
            s16x4 hb4;
#pragma unroll
            for (int r = 0; r < 4; r++) {
                float er = exp2fast(__builtin_fmaf(acc[0][jt][r], NLOG2E, gc0[jt][r]));
                float rr = __builtin_amdgcn_rcpf(1.0f + er);
                float ez = exp2fast(__builtin_fmaf(acc[1][jt][r], NLOG2E, gc1[jt][r]));
                float zz = __builtin_amdgcn_rcpf(1.0f + ez);
                float en = exp2fast(__builtin_fmaf(rr * acc[2][jt][r], LOG2E2, gc2[jt][r]));
                float nn = __builtin_fmaf(__builtin_amdgcn_rcpf(1.0f + en), -2.0f, 1.0f);
                float hnew = __builtin_fmaf(zz, hreg[jt][r] - nn, nn);
                hreg[jt][r] = hnew;
                hb4[r] = (short)f2bf(hnew);
            }
            *(s16x4*)&hn[wrow + jt * 16] = hb4;              // ds_write_b64
            if (h1_out) *(s16x4*)&h1_out[hof + jt * 16] = hb4;
        }
        hof += HID;

        if (hlast && t == SEQT - 1) {
#pragma unroll
            for (int jt = 0; jt < 2; jt++) {
                f32x4 hv = { hreg[jt][0], hreg[jt][1], hreg[jt][2], hreg[jt][3] };
                *(f32x4*)&hlast[(b0 + col) * HID + jbase + jt * 16 + quad * 4] = hv;
            }
        }

        __syncthreads();
    }
}

// out[256,118] = hlast[256,256] @ fcW[118,256]^T + fcb
__global__ __launch_bounds__(128) void fc_kernel(
    const float* __restrict__ hlast, const float* __restrict__ W,
    const float* __restrict__ b, float* __restrict__ out)
{
    __shared__ float hsm[HID];
    int bidx = blockIdx.x;
    for (int i = threadIdx.x; i < HID; i += 128) hsm[i] = hlast[(size_t)bidx * HID + i];
    __syncthreads();
    int o = threadIdx.x;
    if (o < OUTD) {
        float acc = b[o];
        const float* wrow = W + (size_t)o * HID;
#pragma unroll 4
        for (int k = 0; k < HID; k++) acc += hsm[k] * wrow[k];
        out[(size_t)bidx * OUTD + o] = acc;
    }
}

extern "C" void kernel_launch(void* const* d_in, const int* in_sizes, int n_in,
                              void* d_out, int out_size, void* d_ws, size_t ws_size,
                              hipStream_t stream) {
    const float* x    = (const float*)d_in[0];
    const float* Wih0 = (const float*)d_in[1];
    const float* Whh0 = (const float*)d_in[2];
    const float* bih0 = (const float*)d_in[3];
    const float* bhh0 = (const float*)d_in[4];
    const float* Wih1 = (const float*)d_in[5];
    const float* Whh1 = (const float*)d_in[6];
    const float* bih1 = (const float*)d_in[7];
    const float* bhh1 = (const float*)d_in[8];
    const float* fcW  = (const float*)d_in[9];
    const float* fcb  = (const float*)d_in[10];
    float* out = (float*)d_out;

    char* ws = (char*)d_ws;
    size_t off = 0;
    auto walloc = [&](size_t bytes) {
        void* p = ws + off;
        off = (off + bytes + 255) & ~(size_t)255;
        return p;
    };

    const int M = BATCH * SEQT;                       // 51200
    float*          gxb  = (float*)         walloc((size_t)M * G3 * 4);   // 157.3 MB
    unsigned short* h1b  = (unsigned short*)walloc((size_t)M * HID * 2);  //  26.2 MB
    unsigned short* w0b  = (unsigned short*)walloc((size_t)W0SZ * 2);
    unsigned short* wh0b = (unsigned short*)walloc((size_t)WHSZ * 2);
    unsigned short* w1b  = (unsigned short*)walloc((size_t)WHSZ * 2);
    unsigned short* wh1b = (unsigned short*)walloc((size_t)WHSZ * 2);
    float*          bc0  = (float*)         walloc(G3 * 4);
    float*          bc1  = (float*)         walloc(G3 * 4);
    float*          hlast= (float*)         walloc((size_t)BATCH * HID * 4);

    cvt_weights <<<2688, 256, 0, stream>>>(Wih0, Whh0, Wih1, Whh1, w0b, wh0b, w1b, wh1b);
    combine_bias<<<6,    256, 0, stream>>>(bih0, bhh0, bih1, bhh1, bc0, bc1);

    // layer 0 (A = x, fp32 read + in-register cvt)
    gemm_bf16<IND, true ><<<M / 64, 256, 0, stream>>>(x, w0b, bc0, gxb);
    gru_scan<<<16, 512, 0, stream>>>(gxb, wh0b, bhh0, h1b, nullptr);

    // layer 1
    gemm_bf16<HID, false><<<M / 64, 256, 0, stream>>>(h1b, w1b, bc1, gxb);
    gru_scan<<<16, 512, 0, stream>>>(gxb, wh1b, bhh1, nullptr, hlast);

    fc_kernel<<<BATCH, 128, 0, stream>>>(hlast, fcW, fcb, out);
}

// Round 9
// 1219.434 us; speedup vs baseline: 4.9101x; 1.0591x over previous
//
#include <hip/hip_runtime.h>
#include <hip/hip_bf16.h>
#include <stdint.h>

// Problem constants
#define BATCH 256
#define SEQT  200
#define IND   128
#define HID   256
#define G3    768   // 3*HID
#define OUTD  118

#define HSTRIDE 264  // h-state LDS row stride in shorts (16B-aligned)
#define W0SZ (G3*IND)
#define WHSZ (G3*HID)

#define LOG2E  1.44269504f
#define NLOG2E (-1.44269504f)
#define LOG2E2 2.88539008f

typedef short  s16x4  __attribute__((ext_vector_type(4)));
typedef short  short8 __attribute__((ext_vector_type(8)));
typedef float  f32x4  __attribute__((ext_vector_type(4)));
typedef int    i32x4  __attribute__((ext_vector_type(4)));

__device__ __forceinline__ float exp2fast(float x) {
#if __has_builtin(__builtin_amdgcn_exp2f)
    return __builtin_amdgcn_exp2f(x);
#else
    return exp2f(x);
#endif
}

__device__ __forceinline__ unsigned short f2bf(float x) {
    union { float f; uint32_t u; } v; v.f = x;
    uint32_t u = v.u;
    u += 0x7FFF + ((u >> 16) & 1);   // round-to-nearest-even
    return (unsigned short)(u >> 16);
}

// One fused conversion kernel for all four weight matrices.
__global__ void cvt_weights(const float* __restrict__ w0,  const float* __restrict__ wh0,
                            const float* __restrict__ w1,  const float* __restrict__ wh1,
                            unsigned short* __restrict__ o0,  unsigned short* __restrict__ oh0,
                            unsigned short* __restrict__ o1,  unsigned short* __restrict__ oh1) {
    int i = blockIdx.x * blockDim.x + threadIdx.x;
    const int n = W0SZ + 3 * WHSZ;
    int stride = gridDim.x * blockDim.x;
    for (; i < n; i += stride) {
        int j = i;
        if (j < W0SZ) { o0[j] = f2bf(w0[j]); continue; }
        j -= W0SZ;
        if (j < WHSZ) { oh0[j] = f2bf(wh0[j]); continue; }
        j -= WHSZ;
        if (j < WHSZ) { o1[j] = f2bf(w1[j]); continue; }
        j -= WHSZ;
        oh1[j] = f2bf(wh1[j]);
    }
}

// bc = bih + bhh for r,z gates (j < 512); bc = bih for n gate. Both layers.
__global__ void combine_bias(const float* __restrict__ bih0, const float* __restrict__ bhh0,
                             const float* __restrict__ bih1, const float* __restrict__ bhh1,
                             float* __restrict__ bc0, float* __restrict__ bc1) {
    int i = blockIdx.x * blockDim.x + threadIdx.x;
    if (i < G3) bc0[i] = bih0[i] + (i < 2 * HID ? bhh0[i] : 0.0f);
    else if (i < 2 * G3) {
        int j = i - G3;
        bc1[j] = bih1[j] + (j < 2 * HID ? bhh1[j] : 0.0f);
    }
}

// C[M,768] = scale[g] * (A[M,K] @ Bt[768,K]^T + bias[g])
// scale = -log2e (r,z) / +2*log2e (n): pre-scaled exp2 args for gru_scan.
template<int K, bool AF32>
__global__ __launch_bounds__(256) void gemm_bf16(
    const void* __restrict__ Av,
    const unsigned short* __restrict__ Bt,
    const float* __restrict__ bias,
    float* __restrict__ C)
{
    const int mt   = blockIdx.x;
    const int wave = threadIdx.x >> 6;
    const int lane = threadIdx.x & 63;
    const int col  = lane & 15;
    const int quad = lane >> 4;
    const int m0   = mt * 64 + wave * 16;
    constexpr int KS = K / 32;

    short8 a[KS];
    if constexpr (AF32) {
        const float* arow = (const float*)Av + (size_t)(m0 + col) * K;
#pragma unroll
        for (int ks = 0; ks < KS; ks++) {
            f32x4 lo = *(const f32x4*)(arow + ks * 32 + quad * 8);
            f32x4 hi = *(const f32x4*)(arow + ks * 32 + quad * 8 + 4);
#pragma unroll
            for (int e = 0; e < 4; e++) {
                a[ks][e]     = (short)f2bf(lo[e]);
                a[ks][e + 4] = (short)f2bf(hi[e]);
            }
        }
    } else {
        const unsigned short* arow = (const unsigned short*)Av + (size_t)(m0 + col) * K;
#pragma unroll
        for (int ks = 0; ks < KS; ks++)
            a[ks] = *(const short8*)(arow + ks * 32 + quad * 8);
    }

#pragma unroll
    for (int nb = 0; nb < 6; nb++) {
        const float scl = (nb < 4) ? NLOG2E : LOG2E2;
        f32x4 acc[8];
#pragma unroll
        for (int nt = 0; nt < 8; nt++) acc[nt] = (f32x4)(0.0f);
#pragma unroll
        for (int ks = 0; ks < KS; ks++) {
#pragma unroll
            for (int nt = 0; nt < 8; nt++) {
                const unsigned short* bp =
                    Bt + (size_t)(nb * 128 + nt * 16 + col) * K + ks * 32 + quad * 8;
                short8 b = *(const short8*)bp;
                acc[nt] = __builtin_amdgcn_mfma_f32_16x16x32_bf16(a[ks], b, acc[nt], 0, 0, 0);
            }
        }
#pragma unroll
        for (int nt = 0; nt < 8; nt++) {
            int g = nb * 128 + nt * 16 + col;
            float bia = bias[g];
#pragma unroll
            for (int r = 0; r < 4; r++) {
                int m = m0 + quad * 4 + r;
                C[(size_t)m * G3 + g] = (acc[nt][r] + bia) * scl;
            }
        }
    }
}

// GRU scan, transposed-D version. 16 WGs x 512 threads (8 waves, 2/SIMD).
// WG owns batches [wg*16,+16); wave owns 32 j-cols (jt0/jt1) x 3 gates.
// MFMA: A = Whh fragment (m=j), B = h fragment (n=batch) => D[m=j][n=batch]:
// lane owns batch = lane&15, j = jbase + jt*16 + quad*4 + r (4 CONSECUTIVE j).
// => LDS h-writes are ds_write_b64, gx loads are f32x4, h1/hlast vectorized.
// Weights: r,z (both jt) + n jt0 = 160 regs pinned ONCE in arch VGPRs ("+v":
// 160 + ~86 working = ~246 <= 256, fits with NO AGPR homes -> no per-use
// v_accvgpr_read churn, unlike "+a" in round 8).
// n jt1 in LDS (64KB). h double-buffered in LDS; 1 barrier/step.
__global__ __launch_bounds__(512, 2) void gru_scan(
    const float* __restrict__ gx,            // [B*T,768]: r,z scaled -log2e; n scaled 2log2e
    const unsigned short* __restrict__ Whh,  // [768,256] bf16
    const float* __restrict__ bhh,           // [768] (only n-part used)
    unsigned short* __restrict__ h1_out,     // [B*T,256] bf16 or nullptr
    float* __restrict__ hlast)               // [B,256] fp32 or nullptr
{
    __shared__ unsigned short hs[2][16 * HSTRIDE];   // 16,896 B
    __shared__ unsigned short wn1[8 * 8 * 512];      // 65,536 B (n-gate jt1)

    const int b0    = blockIdx.x * 16;
    const int tid   = threadIdx.x;
    const int wave  = tid >> 6;
    const int lane  = tid & 63;
    const int col   = lane & 15;   // = batch-in-tile (D col) and A-frag m (j row)
    const int quad  = lane >> 4;
    const int jbase = wave * 32;

    // r,z weights (both jt) + n jt0 -> 160 regs
    i32x4 wrz[2][2][8];   // [gate][jt][ks]
#pragma unroll
    for (int g = 0; g < 2; g++)
#pragma unroll
        for (int jt = 0; jt < 2; jt++)
#pragma unroll
            for (int ks = 0; ks < 8; ks++)
                wrz[g][jt][ks] = *(const i32x4*)(
                    Whh + (size_t)(g * HID + jbase + jt * 16 + col) * HID + ks * 32 + quad * 8);
    i32x4 wn0[8];
#pragma unroll
    for (int ks = 0; ks < 8; ks++)
        wn0[ks] = *(const i32x4*)(
            Whh + (size_t)(2 * HID + jbase + col) * HID + ks * 32 + quad * 8);

    // pin ONCE in arch VGPRs: opaque asm result -> cannot be re-loaded,
    // no AGPR home -> no per-use copies
#pragma unroll
    for (int g = 0; g < 2; g++)
#pragma unroll
        for (int jt = 0; jt < 2; jt++)
#pragma unroll
            for (int ks = 0; ks < 8; ks++)
                asm volatile("" : "+v"(wrz[g][jt][ks]));
#pragma unroll
    for (int ks = 0; ks < 8; ks++)
        asm volatile("" : "+v"(wn0[ks]));

    // n-gate jt1 -> LDS, per-lane-contiguous fragment order (conflict-free)
    const int wnbase = wave * 4096 + lane * 8;   // shorts
#pragma unroll
    for (int ks = 0; ks < 8; ks++)
        *(short8*)&wn1[wnbase + ks * 512] =
            *(const short8*)(Whh + (size_t)(2 * HID + jbase + 16 + col) * HID + ks * 32 + quad * 8);

    for (int i = tid; i < 16 * HSTRIDE; i += 512) hs[0][i] = 0;

    float hreg[2][4] = {};          // [jt][r]: h for batch=b0+col, j=jbase+jt*16+quad*4+r
    f32x4 bhnv[2];                  // n-gate bhh, 4 consecutive j
#pragma unroll
    for (int jt = 0; jt < 2; jt++)
        bhnv[jt] = *(const f32x4*)(bhh + 2 * HID + jbase + jt * 16 + quad * 4);

    // lane-private pointers (batch = b0+col)
    const float* gpp = gx + (size_t)(b0 + col) * SEQT * G3 + jbase + quad * 4;
    int hof = (b0 + col) * SEQT * HID + jbase + quad * 4;

    const int bbase = col * HSTRIDE + quad * 8;              // h B-frag read base (shorts)
    const int wrow  = col * HSTRIDE + jbase + quad * 4;      // h write base (shorts)

    __syncthreads();

    for (int t = 0; t < SEQT; t++) {
        const unsigned short* hc = hs[t & 1];
        unsigned short*       hn = hs[(t & 1) ^ 1];

        // gx loads at step top; consumed in the gate phase ~1.5k cycles later
        f32x4 gc0[2], gc1[2], gc2[2];
#pragma unroll
        for (int jt = 0; jt < 2; jt++) {
            gc0[jt] = *(const f32x4*)(gpp + jt * 16);
            gc1[jt] = *(const f32x4*)(gpp + HID + jt * 16);
            gc2[jt] = *(const f32x4*)(gpp + 2 * HID + jt * 16);
        }
        gpp += G3;

        f32x4 acc[3][2];
#pragma unroll
        for (int jt = 0; jt < 2; jt++) {
            acc[0][jt] = (f32x4)(0.0f);
            acc[1][jt] = (f32x4)(0.0f);
            acc[2][jt] = bhnv[jt];    // seed n with bhh_n (free add)
        }

#pragma unroll
        for (int ks = 0; ks < 8; ks++) {
            short8 hfrag = *(const short8*)(&hc[bbase + ks * 32]);
            acc[0][0] = __builtin_amdgcn_mfma_f32_16x16x32_bf16(__builtin_bit_cast(short8, wrz[0][0][ks]), hfrag, acc[0][0], 0, 0, 0);
            acc[0][1] = __builtin_amdgcn_mfma_f32_16x16x32_bf16(__builtin_bit_cast(short8, wrz[0][1][ks]), hfrag, acc[0][1], 0, 0, 0);
            acc[1][0] = __builtin_amdgcn_mfma_f32_16x16x32_bf16(__builtin_bit_cast(short8, wrz[1][0][ks]), hfrag, acc[1][0], 0, 0, 0);
            acc[1][1] = __builtin_amdgcn_mfma_f32_16x16x32_bf16(__builtin_bit_cast(short8, wrz[1][1][ks]), hfrag, acc[1][1], 0, 0, 0);
            acc[2][0] = __builtin_amdgcn_mfma_f32_16x16x32_bf16(__builtin_bit_cast(short8, wn0[ks]),       hfrag, acc[2][0], 0, 0, 0);
            short8 b1 = *(const short8*)&wn1[wnbase + ks * 512];
            acc[2][1] = __builtin_amdgcn_mfma_f32_16x16x32_bf16(b1, hfrag, acc[2][1], 0, 0, 0);
        }

        // gate math; lane's 8 outputs are (batch=b0+col, j=jbase+jt*16+quad*4+r)
#pragma unroll
        for (int jt = 0; jt < 2; jt++) {
            s16x4 hb4;
#pragma unroll
            for (int r = 0; r < 4; r++) {
                float er = exp2fast(__builtin_fmaf(acc[0][jt][r], NLOG2E, gc0[jt][r]));
                float rr = __builtin_amdgcn_rcpf(1.0f + er);
                float ez = exp2fast(__builtin_fmaf(acc[1][jt][r], NLOG2E, gc1[jt][r]));
                float zz = __builtin_amdgcn_rcpf(1.0f + ez);
                float en = exp2fast(__builtin_fmaf(rr * acc[2][jt][r], LOG2E2, gc2[jt][r]));
                float nn = __builtin_fmaf(__builtin_amdgcn_rcpf(1.0f + en), -2.0f, 1.0f);
                float hnew = __builtin_fmaf(zz, hreg[jt][r] - nn, nn);
                hreg[jt][r] = hnew;
                hb4[r] = (short)f2bf(hnew);
            }
            *(s16x4*)&hn[wrow + jt * 16] = hb4;              // ds_write_b64
            if (h1_out) *(s16x4*)&h1_out[hof + jt * 16] = hb4;
        }
        hof += HID;

        if (hlast && t == SEQT - 1) {
#pragma unroll
            for (int jt = 0; jt < 2; jt++) {
                f32x4 hv = { hreg[jt][0], hreg[jt][1], hreg[jt][2], hreg[jt][3] };
                *(f32x4*)&hlast[(b0 + col) * HID + jbase + jt * 16 + quad * 4] = hv;
            }
        }

        __syncthreads();
    }
}

// out[256,118] = hlast[256,256] @ fcW[118,256]^T + fcb
__global__ __launch_bounds__(128) void fc_kernel(
    const float* __restrict__ hlast, const float* __restrict__ W,
    const float* __restrict__ b, float* __restrict__ out)
{
    __shared__ float hsm[HID];
    int bidx = blockIdx.x;
    for (int i = threadIdx.x; i < HID; i += 128) hsm[i] = hlast[(size_t)bidx * HID + i];
    __syncthreads();
    int o = threadIdx.x;
    if (o < OUTD) {
        float acc = b[o];
        const float* wrow = W + (size_t)o * HID;
#pragma unroll 4
        for (int k = 0; k < HID; k++) acc += hsm[k] * wrow[k];
        out[(size_t)bidx * OUTD + o] = acc;
    }
}

extern "C" void kernel_launch(void* const* d_in, const int* in_sizes, int n_in,
                              void* d_out, int out_size, void* d_ws, size_t ws_size,
                              hipStream_t stream) {
    const float* x    = (const float*)d_in[0];
    const float* Wih0 = (const float*)d_in[1];
    const float* Whh0 = (const float*)d_in[2];
    const float* bih0 = (const float*)d_in[3];
    const float* bhh0 = (const float*)d_in[4];
    const float* Wih1 = (const float*)d_in[5];
    const float* Whh1 = (const float*)d_in[6];
    const float* bih1 = (const float*)d_in[7];
    const float* bhh1 = (const float*)d_in[8];
    const float* fcW  = (const float*)d_in[9];
    const float* fcb  = (const float*)d_in[10];
    float* out = (float*)d_out;

    char* ws = (char*)d_ws;
    size_t off = 0;
    auto walloc = [&](size_t bytes) {
        void* p = ws + off;
        off = (off + bytes + 255) & ~(size_t)255;
        return p;
    };

    const int M = BATCH * SEQT;                       // 51200
    float*          gxb  = (float*)         walloc((size_t)M * G3 * 4);   // 157.3 MB
    unsigned short* h1b  = (unsigned short*)walloc((size_t)M * HID * 2);  //  26.2 MB
    unsigned short* w0b  = (unsigned short*)walloc((size_t)W0SZ * 2);
    unsigned short* wh0b = (unsigned short*)walloc((size_t)WHSZ * 2);
    unsigned short* w1b  = (unsigned short*)walloc((size_t)WHSZ * 2);
    unsigned short* wh1b = (unsigned short*)walloc((size_t)WHSZ * 2);
    float*          bc0  = (float*)         walloc(G3 * 4);
    float*          bc1  = (float*)         walloc(G3 * 4);
    float*          hlast= (float*)         walloc((size_t)BATCH * HID * 4);

    cvt_weights <<<2688, 256, 0, stream>>>(Wih0, Whh0, Wih1, Whh1, w0b, wh0b, w1b, wh1b);
    combine_bias<<<6,    256, 0, stream>>>(bih0, bhh0, bih1, bhh1, bc0, bc1);

    // layer 0 (A = x, fp32 read + in-register cvt)
    gemm_bf16<IND, true ><<<M / 64, 256, 0, stream>>>(x, w0b, bc0, gxb);
    gru_scan<<<16, 512, 0, stream>>>(gxb, wh0b, bhh0, h1b, nullptr);

    // layer 1
    gemm_bf16<HID, false><<<M / 64, 256, 0, stream>>>(h1b, w1b, bc1, gxb);
    gru_scan<<<16, 512, 0, stream>>>(gxb, wh1b, bhh1, nullptr, hlast);

    fc_kernel<<<BATCH, 128, 0, stream>>>(hlast, fcW, fcb, out);
}